// Round 9
// baseline (151.441 us; speedup 1.0000x reference)
//
#include <hip/hip_runtime.h>

// Causal single-head attention, B=4, S=4096, D=128, fp32 in/out.
// R9: occupancy push. fa_fwd: single 32KB LDS buffer (2-barrier glds staging,
// 4 blocks/CU co-residency hides load latency), Q read directly from fp32
// (no Qbf), bf16 partials (halves Op traffic). 32x32x16 MFMA core from R8.

#define B_   4
#define S_   4096
#define D_   128
#define NT_  64             // 64-key blobs per batch (prep granularity)
#define QT_  32             // q-tiles per batch (BM=128)
#define RMAX 4
#define BLOB_SHORTS 16384   // 32 KB per (b,kt): [K img 16KB][V^T img 16KB]
#define MASKVAL (-1.0e30f)

typedef __attribute__((ext_vector_type(8))) short bf16x8;
typedef __attribute__((ext_vector_type(4))) float f32x4;
typedef __attribute__((ext_vector_type(16))) float f32x16;

__device__ __forceinline__ short f2bf(float x) {
    unsigned u = __builtin_bit_cast(unsigned, x);
    unsigned r = (u + 0x7fffu + ((u >> 16) & 1u)) >> 16;
    return (short)r;
}
__device__ __forceinline__ float ex2(float x) { return __builtin_amdgcn_exp2f(x); }
__device__ __forceinline__ unsigned pkbf(float lo, float hi) {
    return (unsigned)(unsigned short)f2bf(lo) | ((unsigned)(unsigned short)f2bf(hi) << 16);
}
__device__ __forceinline__ float bf2f(short s) {
    return __builtin_bit_cast(float, ((unsigned)(unsigned short)s) << 16);
}
__device__ __forceinline__ void gl_lds16(const short* g, short* l) {
    __builtin_amdgcn_global_load_lds(
        (const __attribute__((address_space(1))) unsigned int*)g,
        (__attribute__((address_space(3))) unsigned int*)l, 16, 0, 0);
}

// ---------------- prep: 2048 blocks, K/V only ------------------------------
// K image: row n (64) x 16 granules of 8 bf16; source granule G at
//   p = (G&8) | ((G&7) ^ (n&7)).
// V image: row d (128) x 8 granules; source granule G (= k-octet) at
//   p = G ^ (d&7); granule holds V[kt*64+G*8+i][d], i=0..7.
__global__ __launch_bounds__(256) void prep(const float* __restrict__ Kg,
                                            const float* __restrict__ Vg,
                                            short* __restrict__ KV)
{
    __shared__ short vt[64][40];
    const int id  = blockIdx.x;
    const int tid = threadIdx.x;

    if (id < 1024) {
        const int b = id & 3, tile = (id >> 2) & 63, q4 = id >> 8;
        const int n = q4 * 16 + (tid >> 4);
        const int G = tid & 15;
        const size_t rowoff = ((size_t)b * S_ + (size_t)tile * 64 + n) * D_ + G * 8;
        short* blob = KV + (size_t)(b * NT_ + tile) * BLOB_SHORTS;
        float4 a = *reinterpret_cast<const float4*>(Kg + rowoff);
        float4 c = *reinterpret_cast<const float4*>(Kg + rowoff + 4);
        bf16x8 v;
        v[0] = f2bf(a.x); v[1] = f2bf(a.y); v[2] = f2bf(a.z); v[3] = f2bf(a.w);
        v[4] = f2bf(c.x); v[5] = f2bf(c.y); v[6] = f2bf(c.z); v[7] = f2bf(c.w);
        const int p = (G & 8) | ((G & 7) ^ (n & 7));
        *reinterpret_cast<bf16x8*>(blob + n * 128 + p * 8) = v;
    } else {
        const int u = id - 1024;
        const int b = u & 3, tile = (u >> 2) & 63, dq = u >> 8;
        short* blob = KV + (size_t)(b * NT_ + tile) * BLOB_SHORTS;
        {
            const int n = tid >> 2, c8 = tid & 3;
            const size_t off = ((size_t)b * S_ + (size_t)tile * 64 + n) * D_ + dq * 32 + c8 * 8;
            float4 a = *reinterpret_cast<const float4*>(Vg + off);
            float4 c = *reinterpret_cast<const float4*>(Vg + off + 4);
            bf16x8 v;
            v[0] = f2bf(a.x); v[1] = f2bf(a.y); v[2] = f2bf(a.z); v[3] = f2bf(a.w);
            v[4] = f2bf(c.x); v[5] = f2bf(c.y); v[6] = f2bf(c.z); v[7] = f2bf(c.w);
            *reinterpret_cast<bf16x8*>(&vt[n][c8 * 8]) = v;
        }
        __syncthreads();
        {
            const int dl = tid >> 3, G = tid & 7;
            const int d  = dq * 32 + dl;
            bf16x8 g;
#pragma unroll
            for (int i = 0; i < 8; ++i) g[i] = vt[G * 8 + i][dl];
            const int p = G ^ (d & 7);
            *reinterpret_cast<bf16x8*>(blob + 8192 + d * 64 + p * 8) = g;
        }
    }
}

// ---------------- fa_fwd: 256 threads, 4 waves x 32 q-rows, 32x32x16 MFMA --
// Layouts (32x32x16 bf16 MFMA):
//   A/B: row(col) = lane&31, k = (lane>>5)*8 + j
//   C/D: col = lane&31, row = (reg&3) + 8*(reg>>2) + 4*(lane>>5)
// S^T = K*Q^T  -> C cols = q (per-lane softmax, alpha scalar)
// O^T = V^T*P^T -> C cols = q (per-lane 1/l)
template<bool SPLIT>
__global__ __launch_bounds__(256, 4) void fa_fwd(const float* __restrict__ Qg,
                                                 const short* __restrict__ KV,
                                                 float* __restrict__ Og,
                                                 short* __restrict__ Opb,
                                                 float* __restrict__ Ml,
                                                 int R)
{
    __shared__ short lkv[BLOB_SHORTS];   // single 32 KB tile buffer

    const int tid  = threadIdx.x;
    const int wv   = tid >> 6;      // 0..3: q-rows [wv*32, wv*32+32)
    const int lane = tid & 63;
    const int col  = lane & 31;
    const int half = lane >> 5;
    const int c7   = col & 7;

    int batch, t, lo, hi, chunk_id;
    {
        const int id = blockIdx.x;
        batch = id & 3;
        if (SPLIT) {
            int u = id >> 2;
            int tt = u / R;
            int r  = u - tt * R;
            t  = QT_ - 1 - tt;                 // heavy q-tiles dispatch first
            const int nk = 2 * t + 2;
            lo = r * nk / R;
            hi = (r + 1) * nk / R;
            chunk_id = (batch * QT_ + t) * R + r;
            if (lo >= hi) return;              // block-uniform, before barriers
        } else {
            t  = QT_ - 1 - (id >> 2);
            lo = 0; hi = 2 * t + 2; chunk_id = 0;
        }
    }

    // Q fragments straight from fp32 global, scale folded:
    // q = t*128 + wv*32 + col, qf[c] = Q[q][16c + 8*half .. +8) * SC
    bf16x8 qf[8];
    {
        const float SC = 0.12751740f;   // log2(e)/sqrt(128)
        const float* qp = Qg + ((size_t)batch * S_ + (size_t)t * 128 + wv * 32 + col) * D_ + half * 8;
#pragma unroll
        for (int c = 0; c < 8; ++c) {
            float4 a = *reinterpret_cast<const float4*>(qp + c * 16);
            float4 b = *reinterpret_cast<const float4*>(qp + c * 16 + 4);
            bf16x8 v;
            v[0] = f2bf(a.x * SC); v[1] = f2bf(a.y * SC); v[2] = f2bf(a.z * SC); v[3] = f2bf(a.w * SC);
            v[4] = f2bf(b.x * SC); v[5] = f2bf(b.y * SC); v[6] = f2bf(b.z * SC); v[7] = f2bf(b.w * SC);
            qf[c] = v;
        }
    }

    f32x16 acc[4];   // O^T tiles: rows d = dt*32.., cols q
#pragma unroll
    for (int i = 0; i < 4; ++i)
#pragma unroll
        for (int r = 0; r < 16; ++r) acc[i][r] = 0.f;
    float mrun = MASKVAL, lrun = 0.f;   // per-lane, q-row = col

    const size_t tilebase = (size_t)batch * NT_ * BLOB_SHORTS;
    // 256 threads x 8 x 16B = 32 KB blob
#define STAGE(KT) do {                                                        \
        const short* g_ = KV + tilebase + (size_t)(KT) * BLOB_SHORTS + tid * 8;\
        short* l_ = lkv + tid * 8;                                            \
        _Pragma("unroll")                                                     \
        for (int c_ = 0; c_ < 8; ++c_)                                        \
            gl_lds16(g_ + c_ * 2048, l_ + c_ * 2048);                         \
    } while (0)

    for (int kt = lo; kt < hi; ++kt) {
        __syncthreads();           // all waves done reading lkv (prev iter)
        STAGE(kt);
        __syncthreads();           // vmcnt(0) drain: tile kt visible

        const short* lk = lkv;            // K image
        const short* lv = lkv + 8192;     // V^T image

        // ---- S^T = K * Q^T : st[kt32] = [32 k][32 q]
        f32x16 st[2];
#pragma unroll
        for (int i = 0; i < 2; ++i)
#pragma unroll
            for (int r = 0; r < 16; ++r) st[i][r] = 0.f;
#pragma unroll
        for (int c = 0; c < 8; ++c) {
            const int G = 2 * c + half;
            const int p = (G & 8) | ((G & 7) ^ c7);
#pragma unroll
            for (int kt32 = 0; kt32 < 2; ++kt32) {
                const int n = kt32 * 32 + col;
                bf16x8 kf = *reinterpret_cast<const bf16x8*>(lk + n * 128 + p * 8);
                st[kt32] = __builtin_amdgcn_mfma_f32_32x32x16_bf16(kf, qf[c], st[kt32], 0, 0, 0);
            }
        }

        // ---- causal mask (last two k-tiles of this q-tile only)
        if (kt >= 2 * t) {
            const int kbase = (kt - 2 * t) * 64;   // 0 or 64
            const int qloc  = wv * 32 + col;
#pragma unroll
            for (int kt32 = 0; kt32 < 2; ++kt32)
#pragma unroll
                for (int r = 0; r < 16; ++r) {
                    const int kl = kt32 * 32 + (r & 3) + 8 * (r >> 2) + 4 * half;
                    if (kbase + kl > qloc) st[kt32][r] = MASKVAL;
                }
        }

        // ---- online softmax: row = col, per-lane + 1 shfl
        float mx = MASKVAL;
#pragma unroll
        for (int i = 0; i < 2; ++i)
#pragma unroll
            for (int r = 0; r < 16; ++r) mx = fmaxf(mx, st[i][r]);
        mx = fmaxf(mx, __shfl_xor(mx, 32));
        const float mnew = fmaxf(mrun, mx);
        const float al   = ex2(mrun - mnew);   // finite-finite: never NaN
        mrun = mnew;
        float sum = 0.f;
#pragma unroll
        for (int i = 0; i < 2; ++i)
#pragma unroll
            for (int r = 0; r < 16; ++r) {
                float pv = ex2(st[i][r] - mnew);
                st[i][r] = pv;
                sum += pv;
            }
        sum += __shfl_xor(sum, 32);
        lrun = lrun * al + sum;
#pragma unroll
        for (int i = 0; i < 4; ++i)
#pragma unroll
            for (int r = 0; r < 16; ++r) acc[i][r] *= al;   // al per-lane

        // ---- PV: O^T += V^T * P^T, P^T via 2 shfl_xor(32) per k-16-step
#pragma unroll
        for (int kt32 = 0; kt32 < 2; ++kt32) {
            unsigned pw[4][2];
#pragma unroll
            for (int w = 0; w < 4; ++w) {
                pw[w][0] = pkbf(st[kt32][4 * w],     st[kt32][4 * w + 1]);
                pw[w][1] = pkbf(st[kt32][4 * w + 2], st[kt32][4 * w + 3]);
            }
#pragma unroll
            for (int s1 = 0; s1 < 2; ++s1) {
                unsigned snd0 = pw[2 * s1 + 1 - half][0];
                unsigned snd1 = pw[2 * s1 + 1 - half][1];
                unsigned rcv0 = __shfl_xor((int)snd0, 32);
                unsigned rcv1 = __shfl_xor((int)snd1, 32);
                unsigned own0 = pw[2 * s1 + half][0];
                unsigned own1 = pw[2 * s1 + half][1];
                int4 wi;
                wi.x = (int)(half ? rcv0 : own0);
                wi.y = (int)(half ? rcv1 : own1);
                wi.z = (int)(half ? own0 : rcv0);
                wi.w = (int)(half ? own1 : rcv1);
                bf16x8 pf = __builtin_bit_cast(bf16x8, wi);
                const int step = kt32 * 2 + s1;
                const int G = 2 * step + half;
                const int p = G ^ c7;
#pragma unroll
                for (int dt = 0; dt < 4; ++dt) {
                    const int d = dt * 32 + col;
                    bf16x8 vf = *reinterpret_cast<const bf16x8*>(lv + d * 64 + p * 8);
                    acc[dt] = __builtin_amdgcn_mfma_f32_32x32x16_bf16(vf, pf, acc[dt], 0, 0, 0);
                }
            }
        }
    }
#undef STAGE

    // ---- epilogue: acc col=q, row d = dt*32 + 8g + 4half + i
    const int qloc = wv * 32 + col;
    if (SPLIT) {
        short* ob = Opb + (size_t)chunk_id * (128 * D_) + (size_t)qloc * D_;
#pragma unroll
        for (int dt = 0; dt < 4; ++dt)
#pragma unroll
            for (int g = 0; g < 4; ++g) {
                const int d0 = dt * 32 + 8 * g + 4 * half;
                int2 w;
                w.x = (int)pkbf(acc[dt][4 * g],     acc[dt][4 * g + 1]);
                w.y = (int)pkbf(acc[dt][4 * g + 2], acc[dt][4 * g + 3]);
                *reinterpret_cast<int2*>(ob + d0) = w;
            }
        if (half == 0) {
            float* mlb = Ml + (size_t)chunk_id * (128 * 2) + qloc * 2;
            mlb[0] = mrun;
            mlb[1] = lrun;
        }
    } else {
        const float inv = 1.0f / lrun;   // per-lane
        float* og = Og + ((size_t)batch * S_ + (size_t)t * 128 + qloc) * D_;
#pragma unroll
        for (int dt = 0; dt < 4; ++dt)
#pragma unroll
            for (int g = 0; g < 4; ++g) {
                const int d0 = dt * 32 + 8 * g + 4 * half;
                f32x4 v4 = {acc[dt][4 * g] * inv, acc[dt][4 * g + 1] * inv,
                            acc[dt][4 * g + 2] * inv, acc[dt][4 * g + 3] * inv};
                *reinterpret_cast<f32x4*>(og + d0) = v4;
            }
    }
}

// ---------------- merge: 2048 blocks, bf16 partials ------------------------
template<int RR>
__global__ __launch_bounds__(256) void fa_merge(const short* __restrict__ Opb,
                                                const float* __restrict__ Ml,
                                                float* __restrict__ Og)
{
    const int x   = blockIdx.x;
    const int btq = x >> 4;                 // b*QT_ + t
    const int oct = x & 15;
    const int t   = btq & (QT_ - 1);
    const int nk  = 2 * t + 2;
    const int row = oct * 8 + (threadIdx.x >> 5);   // 0..127
    const int cg  = threadIdx.x & 31;               // 4 floats per thread
    const size_t cbase = (size_t)btq * RR;

    float mg = MASKVAL;
#pragma unroll
    for (int r = 0; r < RR; ++r) {
        int lo = r * nk / RR, hi = (r + 1) * nk / RR;
        if (lo < hi) mg = fmaxf(mg, Ml[(cbase + r) * (128 * 2) + row * 2]);
    }
    float l = 0.f;
    f32x4 a = (f32x4){0.f, 0.f, 0.f, 0.f};
#pragma unroll
    for (int r = 0; r < RR; ++r) {
        int lo = r * nk / RR, hi = (r + 1) * nk / RR;
        if (lo >= hi) continue;
        float mr = Ml[(cbase + r) * (128 * 2) + row * 2];
        float lr = Ml[(cbase + r) * (128 * 2) + row * 2 + 1];
        float w  = ex2(mr - mg);   // fully-masked chunk: underflows to 0
        l += lr * w;
        short4 s = *reinterpret_cast<const short4*>(
            Opb + (cbase + r) * (128 * D_) + (size_t)row * D_ + cg * 4);
        a[0] += w * bf2f(s.x);
        a[1] += w * bf2f(s.y);
        a[2] += w * bf2f(s.z);
        a[3] += w * bf2f(s.w);
    }
    *reinterpret_cast<f32x4*>(Og + (size_t)btq * (128 * D_) + row * D_ + cg * 4) = a * (1.0f / l);
}

extern "C" void kernel_launch(void* const* d_in, const int* in_sizes, int n_in,
                              void* d_out, int out_size, void* d_ws, size_t ws_size,
                              hipStream_t stream) {
    const float* q = (const float*)d_in[0];
    const float* k = (const float*)d_in[1];
    const float* v = (const float*)d_in[2];
    float* o = (float*)d_out;

    const size_t KV_BYTES  = (size_t)B_ * NT_ * BLOB_SHORTS * 2;    // 8 MB
    const size_t PREFIX    = KV_BYTES;
    const size_t O_ELEMS   = (size_t)B_ * QT_ * 128 * D_;           // per R-unit
    const size_t ML_FLOATS = (size_t)B_ * QT_ * 128 * 2;
    const size_t PER_R     = O_ELEMS * 2 + ML_FLOATS * 4;           // bf16 Op

    char* ws = (char*)d_ws;
    short* KV = (short*)ws;

    int R = 0;
    if (ws_size > PREFIX) {
        R = (int)((ws_size - PREFIX) / PER_R);
        if (R > RMAX) R = RMAX;
    }

    prep<<<dim3(2048), 256, 0, stream>>>(k, v, KV);

    if (R >= 1) {
        short* Opb = (short*)(ws + PREFIX);
        float* Ml  = (float*)(ws + PREFIX + (size_t)R * O_ELEMS * 2);
        fa_fwd<true><<<dim3(B_ * QT_ * R), 256, 0, stream>>>(q, KV, nullptr, Opb, Ml, R);
        switch (R) {
            case 1: fa_merge<1><<<dim3(B_ * QT_ * 16), 256, 0, stream>>>(Opb, Ml, o); break;
            case 2: fa_merge<2><<<dim3(B_ * QT_ * 16), 256, 0, stream>>>(Opb, Ml, o); break;
            case 3: fa_merge<3><<<dim3(B_ * QT_ * 16), 256, 0, stream>>>(Opb, Ml, o); break;
            default: fa_merge<4><<<dim3(B_ * QT_ * 16), 256, 0, stream>>>(Opb, Ml, o); break;
        }
    } else {
        fa_fwd<false><<<dim3(B_ * QT_), 256, 0, stream>>>(q, KV, o, nullptr, nullptr, 1);
    }
}

// Round 10
// 144.934 us; speedup vs baseline: 1.0449x; 1.0449x over previous
//
#include <hip/hip_runtime.h>

// Causal single-head attention, B=4, S=4096, D=128, fp32 in/out.
// R10 (= R9 + R=8): grid was the occupancy limiter (512 blocks = 2/CU; LDS
// and VGPR allowed 4). R=8 -> 1024 blocks, 4 blocks/CU = 16 waves/CU; the
// single-32KB-buffer staging latency is hidden by co-resident blocks.

#define B_   4
#define S_   4096
#define D_   128
#define NT_  64             // 64-key blobs per batch (prep granularity)
#define QT_  32             // q-tiles per batch (BM=128)
#define RMAX 8
#define BLOB_SHORTS 16384   // 32 KB per (b,kt): [K img 16KB][V^T img 16KB]
#define MASKVAL (-1.0e30f)

typedef __attribute__((ext_vector_type(8))) short bf16x8;
typedef __attribute__((ext_vector_type(4))) float f32x4;
typedef __attribute__((ext_vector_type(16))) float f32x16;

__device__ __forceinline__ short f2bf(float x) {
    unsigned u = __builtin_bit_cast(unsigned, x);
    unsigned r = (u + 0x7fffu + ((u >> 16) & 1u)) >> 16;
    return (short)r;
}
__device__ __forceinline__ float ex2(float x) { return __builtin_amdgcn_exp2f(x); }
__device__ __forceinline__ unsigned pkbf(float lo, float hi) {
    return (unsigned)(unsigned short)f2bf(lo) | ((unsigned)(unsigned short)f2bf(hi) << 16);
}
__device__ __forceinline__ float bf2f(short s) {
    return __builtin_bit_cast(float, ((unsigned)(unsigned short)s) << 16);
}
__device__ __forceinline__ void gl_lds16(const short* g, short* l) {
    __builtin_amdgcn_global_load_lds(
        (const __attribute__((address_space(1))) unsigned int*)g,
        (__attribute__((address_space(3))) unsigned int*)l, 16, 0, 0);
}

// ---------------- prep: 2048 blocks, K/V only (unchanged, verified) --------
// K image: row n (64) x 16 granules of 8 bf16; source granule G at
//   p = (G&8) | ((G&7) ^ (n&7)).
// V image: row d (128) x 8 granules; source granule G (= k-octet) at
//   p = G ^ (d&7); granule holds V[kt*64+G*8+i][d], i=0..7.
__global__ __launch_bounds__(256) void prep(const float* __restrict__ Kg,
                                            const float* __restrict__ Vg,
                                            short* __restrict__ KV)
{
    __shared__ short vt[64][40];
    const int id  = blockIdx.x;
    const int tid = threadIdx.x;

    if (id < 1024) {
        const int b = id & 3, tile = (id >> 2) & 63, q4 = id >> 8;
        const int n = q4 * 16 + (tid >> 4);
        const int G = tid & 15;
        const size_t rowoff = ((size_t)b * S_ + (size_t)tile * 64 + n) * D_ + G * 8;
        short* blob = KV + (size_t)(b * NT_ + tile) * BLOB_SHORTS;
        float4 a = *reinterpret_cast<const float4*>(Kg + rowoff);
        float4 c = *reinterpret_cast<const float4*>(Kg + rowoff + 4);
        bf16x8 v;
        v[0] = f2bf(a.x); v[1] = f2bf(a.y); v[2] = f2bf(a.z); v[3] = f2bf(a.w);
        v[4] = f2bf(c.x); v[5] = f2bf(c.y); v[6] = f2bf(c.z); v[7] = f2bf(c.w);
        const int p = (G & 8) | ((G & 7) ^ (n & 7));
        *reinterpret_cast<bf16x8*>(blob + n * 128 + p * 8) = v;
    } else {
        const int u = id - 1024;
        const int b = u & 3, tile = (u >> 2) & 63, dq = u >> 8;
        short* blob = KV + (size_t)(b * NT_ + tile) * BLOB_SHORTS;
        {
            const int n = tid >> 2, c8 = tid & 3;
            const size_t off = ((size_t)b * S_ + (size_t)tile * 64 + n) * D_ + dq * 32 + c8 * 8;
            float4 a = *reinterpret_cast<const float4*>(Vg + off);
            float4 c = *reinterpret_cast<const float4*>(Vg + off + 4);
            bf16x8 v;
            v[0] = f2bf(a.x); v[1] = f2bf(a.y); v[2] = f2bf(a.z); v[3] = f2bf(a.w);
            v[4] = f2bf(c.x); v[5] = f2bf(c.y); v[6] = f2bf(c.z); v[7] = f2bf(c.w);
            *reinterpret_cast<bf16x8*>(&vt[n][c8 * 8]) = v;
        }
        __syncthreads();
        {
            const int dl = tid >> 3, G = tid & 7;
            const int d  = dq * 32 + dl;
            bf16x8 g;
#pragma unroll
            for (int i = 0; i < 8; ++i) g[i] = vt[G * 8 + i][dl];
            const int p = G ^ (d & 7);
            *reinterpret_cast<bf16x8*>(blob + 8192 + d * 64 + p * 8) = g;
        }
    }
}

// ---------------- fa_fwd: 256 threads, 4 waves x 32 q-rows, 32x32x16 MFMA --
// Layouts (32x32x16 bf16 MFMA):
//   A/B: row(col) = lane&31, k = (lane>>5)*8 + j
//   C/D: col = lane&31, row = (reg&3) + 8*(reg>>2) + 4*(lane>>5)
// S^T = K*Q^T  -> C cols = q (per-lane softmax, alpha scalar)
// O^T = V^T*P^T -> C cols = q (per-lane 1/l)
template<bool SPLIT>
__global__ __launch_bounds__(256, 4) void fa_fwd(const float* __restrict__ Qg,
                                                 const short* __restrict__ KV,
                                                 float* __restrict__ Og,
                                                 short* __restrict__ Opb,
                                                 float* __restrict__ Ml,
                                                 int R)
{
    __shared__ short lkv[BLOB_SHORTS];   // single 32 KB tile buffer

    const int tid  = threadIdx.x;
    const int wv   = tid >> 6;      // 0..3: q-rows [wv*32, wv*32+32)
    const int lane = tid & 63;
    const int col  = lane & 31;
    const int half = lane >> 5;
    const int c7   = col & 7;

    int batch, t, lo, hi, chunk_id;
    {
        const int id = blockIdx.x;
        batch = id & 3;
        if (SPLIT) {
            int u = id >> 2;
            int tt = u / R;
            int r  = u - tt * R;
            t  = QT_ - 1 - tt;                 // heavy q-tiles dispatch first
            const int nk = 2 * t + 2;
            lo = r * nk / R;
            hi = (r + 1) * nk / R;
            chunk_id = (batch * QT_ + t) * R + r;
            if (lo >= hi) return;              // block-uniform, before barriers
        } else {
            t  = QT_ - 1 - (id >> 2);
            lo = 0; hi = 2 * t + 2; chunk_id = 0;
        }
    }

    // Q fragments straight from fp32 global, scale folded:
    // q = t*128 + wv*32 + col, qf[c] = Q[q][16c + 8*half .. +8) * SC
    bf16x8 qf[8];
    {
        const float SC = 0.12751740f;   // log2(e)/sqrt(128)
        const float* qp = Qg + ((size_t)batch * S_ + (size_t)t * 128 + wv * 32 + col) * D_ + half * 8;
#pragma unroll
        for (int c = 0; c < 8; ++c) {
            float4 a = *reinterpret_cast<const float4*>(qp + c * 16);
            float4 b = *reinterpret_cast<const float4*>(qp + c * 16 + 4);
            bf16x8 v;
            v[0] = f2bf(a.x * SC); v[1] = f2bf(a.y * SC); v[2] = f2bf(a.z * SC); v[3] = f2bf(a.w * SC);
            v[4] = f2bf(b.x * SC); v[5] = f2bf(b.y * SC); v[6] = f2bf(b.z * SC); v[7] = f2bf(b.w * SC);
            qf[c] = v;
        }
    }

    f32x16 acc[4];   // O^T tiles: rows d = dt*32.., cols q
#pragma unroll
    for (int i = 0; i < 4; ++i)
#pragma unroll
        for (int r = 0; r < 16; ++r) acc[i][r] = 0.f;
    float mrun = MASKVAL, lrun = 0.f;   // per-lane, q-row = col

    const size_t tilebase = (size_t)batch * NT_ * BLOB_SHORTS;
    // 256 threads x 8 x 16B = 32 KB blob
#define STAGE(KT) do {                                                        \
        const short* g_ = KV + tilebase + (size_t)(KT) * BLOB_SHORTS + tid * 8;\
        short* l_ = lkv + tid * 8;                                            \
        _Pragma("unroll")                                                     \
        for (int c_ = 0; c_ < 8; ++c_)                                        \
            gl_lds16(g_ + c_ * 2048, l_ + c_ * 2048);                         \
    } while (0)

    for (int kt = lo; kt < hi; ++kt) {
        __syncthreads();           // all waves done reading lkv (prev iter)
        STAGE(kt);
        __syncthreads();           // vmcnt(0) drain: tile kt visible

        const short* lk = lkv;            // K image
        const short* lv = lkv + 8192;     // V^T image

        // ---- S^T = K * Q^T : st[kt32] = [32 k][32 q]
        f32x16 st[2];
#pragma unroll
        for (int i = 0; i < 2; ++i)
#pragma unroll
            for (int r = 0; r < 16; ++r) st[i][r] = 0.f;
#pragma unroll
        for (int c = 0; c < 8; ++c) {
            const int G = 2 * c + half;
            const int p = (G & 8) | ((G & 7) ^ c7);
#pragma unroll
            for (int kt32 = 0; kt32 < 2; ++kt32) {
                const int n = kt32 * 32 + col;
                bf16x8 kf = *reinterpret_cast<const bf16x8*>(lk + n * 128 + p * 8);
                st[kt32] = __builtin_amdgcn_mfma_f32_32x32x16_bf16(kf, qf[c], st[kt32], 0, 0, 0);
            }
        }

        // ---- causal mask (last two k-tiles of this q-tile only)
        if (kt >= 2 * t) {
            const int kbase = (kt - 2 * t) * 64;   // 0 or 64
            const int qloc  = wv * 32 + col;
#pragma unroll
            for (int kt32 = 0; kt32 < 2; ++kt32)
#pragma unroll
                for (int r = 0; r < 16; ++r) {
                    const int kl = kt32 * 32 + (r & 3) + 8 * (r >> 2) + 4 * half;
                    if (kbase + kl > qloc) st[kt32][r] = MASKVAL;
                }
        }

        // ---- online softmax: row = col, per-lane + 1 shfl
        float mx = MASKVAL;
#pragma unroll
        for (int i = 0; i < 2; ++i)
#pragma unroll
            for (int r = 0; r < 16; ++r) mx = fmaxf(mx, st[i][r]);
        mx = fmaxf(mx, __shfl_xor(mx, 32));
        const float mnew = fmaxf(mrun, mx);
        const float al   = ex2(mrun - mnew);   // finite-finite: never NaN
        mrun = mnew;
        float sum = 0.f;
#pragma unroll
        for (int i = 0; i < 2; ++i)
#pragma unroll
            for (int r = 0; r < 16; ++r) {
                float pv = ex2(st[i][r] - mnew);
                st[i][r] = pv;
                sum += pv;
            }
        sum += __shfl_xor(sum, 32);
        lrun = lrun * al + sum;
#pragma unroll
        for (int i = 0; i < 4; ++i)
#pragma unroll
            for (int r = 0; r < 16; ++r) acc[i][r] *= al;   // al per-lane

        // ---- PV: O^T += V^T * P^T, P^T via 2 shfl_xor(32) per k-16-step
#pragma unroll
        for (int kt32 = 0; kt32 < 2; ++kt32) {
            unsigned pw[4][2];
#pragma unroll
            for (int w = 0; w < 4; ++w) {
                pw[w][0] = pkbf(st[kt32][4 * w],     st[kt32][4 * w + 1]);
                pw[w][1] = pkbf(st[kt32][4 * w + 2], st[kt32][4 * w + 3]);
            }
#pragma unroll
            for (int s1 = 0; s1 < 2; ++s1) {
                unsigned snd0 = pw[2 * s1 + 1 - half][0];
                unsigned snd1 = pw[2 * s1 + 1 - half][1];
                unsigned rcv0 = __shfl_xor((int)snd0, 32);
                unsigned rcv1 = __shfl_xor((int)snd1, 32);
                unsigned own0 = pw[2 * s1 + half][0];
                unsigned own1 = pw[2 * s1 + half][1];
                int4 wi;
                wi.x = (int)(half ? rcv0 : own0);
                wi.y = (int)(half ? rcv1 : own1);
                wi.z = (int)(half ? own0 : rcv0);
                wi.w = (int)(half ? own1 : rcv1);
                bf16x8 pf = __builtin_bit_cast(bf16x8, wi);
                const int step = kt32 * 2 + s1;
                const int G = 2 * step + half;
                const int p = G ^ c7;
#pragma unroll
                for (int dt = 0; dt < 4; ++dt) {
                    const int d = dt * 32 + col;
                    bf16x8 vf = *reinterpret_cast<const bf16x8*>(lv + d * 64 + p * 8);
                    acc[dt] = __builtin_amdgcn_mfma_f32_32x32x16_bf16(vf, pf, acc[dt], 0, 0, 0);
                }
            }
        }
    }
#undef STAGE

    // ---- epilogue: acc col=q, row d = dt*32 + 8g + 4half + i
    const int qloc = wv * 32 + col;
    if (SPLIT) {
        short* ob = Opb + (size_t)chunk_id * (128 * D_) + (size_t)qloc * D_;
#pragma unroll
        for (int dt = 0; dt < 4; ++dt)
#pragma unroll
            for (int g = 0; g < 4; ++g) {
                const int d0 = dt * 32 + 8 * g + 4 * half;
                int2 w;
                w.x = (int)pkbf(acc[dt][4 * g],     acc[dt][4 * g + 1]);
                w.y = (int)pkbf(acc[dt][4 * g + 2], acc[dt][4 * g + 3]);
                *reinterpret_cast<int2*>(ob + d0) = w;
            }
        if (half == 0) {
            float* mlb = Ml + (size_t)chunk_id * (128 * 2) + qloc * 2;
            mlb[0] = mrun;
            mlb[1] = lrun;
        }
    } else {
        const float inv = 1.0f / lrun;   // per-lane
        float* og = Og + ((size_t)batch * S_ + (size_t)t * 128 + qloc) * D_;
#pragma unroll
        for (int dt = 0; dt < 4; ++dt)
#pragma unroll
            for (int g = 0; g < 4; ++g) {
                const int d0 = dt * 32 + 8 * g + 4 * half;
                f32x4 v4 = {acc[dt][4 * g] * inv, acc[dt][4 * g + 1] * inv,
                            acc[dt][4 * g + 2] * inv, acc[dt][4 * g + 3] * inv};
                *reinterpret_cast<f32x4*>(og + d0) = v4;
            }
    }
}

// ---------------- merge: 2048 blocks, bf16 partials ------------------------
template<int RR>
__global__ __launch_bounds__(256) void fa_merge(const short* __restrict__ Opb,
                                                const float* __restrict__ Ml,
                                                float* __restrict__ Og)
{
    const int x   = blockIdx.x;
    const int btq = x >> 4;                 // b*QT_ + t
    const int oct = x & 15;
    const int t   = btq & (QT_ - 1);
    const int nk  = 2 * t + 2;
    const int row = oct * 8 + (threadIdx.x >> 5);   // 0..127
    const int cg  = threadIdx.x & 31;               // 4 floats per thread
    const size_t cbase = (size_t)btq * RR;

    float mg = MASKVAL;
#pragma unroll
    for (int r = 0; r < RR; ++r) {
        int lo = r * nk / RR, hi = (r + 1) * nk / RR;
        if (lo < hi) mg = fmaxf(mg, Ml[(cbase + r) * (128 * 2) + row * 2]);
    }
    float l = 0.f;
    f32x4 a = (f32x4){0.f, 0.f, 0.f, 0.f};
#pragma unroll
    for (int r = 0; r < RR; ++r) {
        int lo = r * nk / RR, hi = (r + 1) * nk / RR;
        if (lo >= hi) continue;
        float mr = Ml[(cbase + r) * (128 * 2) + row * 2];
        float lr = Ml[(cbase + r) * (128 * 2) + row * 2 + 1];
        float w  = ex2(mr - mg);   // fully-masked chunk: underflows to 0
        l += lr * w;
        short4 s = *reinterpret_cast<const short4*>(
            Opb + (cbase + r) * (128 * D_) + (size_t)row * D_ + cg * 4);
        a[0] += w * bf2f(s.x);
        a[1] += w * bf2f(s.y);
        a[2] += w * bf2f(s.z);
        a[3] += w * bf2f(s.w);
    }
    *reinterpret_cast<f32x4*>(Og + (size_t)btq * (128 * D_) + row * D_ + cg * 4) = a * (1.0f / l);
}

extern "C" void kernel_launch(void* const* d_in, const int* in_sizes, int n_in,
                              void* d_out, int out_size, void* d_ws, size_t ws_size,
                              hipStream_t stream) {
    const float* q = (const float*)d_in[0];
    const float* k = (const float*)d_in[1];
    const float* v = (const float*)d_in[2];
    float* o = (float*)d_out;

    const size_t KV_BYTES  = (size_t)B_ * NT_ * BLOB_SHORTS * 2;    // 8 MB
    const size_t PREFIX    = KV_BYTES;
    const size_t O_ELEMS   = (size_t)B_ * QT_ * 128 * D_;           // per R-unit
    const size_t ML_FLOATS = (size_t)B_ * QT_ * 128 * 2;
    const size_t PER_R     = O_ELEMS * 2 + ML_FLOATS * 4;           // bf16 Op

    char* ws = (char*)d_ws;
    short* KV = (short*)ws;

    int R = 0;
    if (ws_size > PREFIX) {
        R = (int)((ws_size - PREFIX) / PER_R);
        if (R > RMAX) R = RMAX;
    }

    prep<<<dim3(2048), 256, 0, stream>>>(k, v, KV);

    if (R >= 1) {
        short* Opb = (short*)(ws + PREFIX);
        float* Ml  = (float*)(ws + PREFIX + (size_t)R * O_ELEMS * 2);
        fa_fwd<true><<<dim3(B_ * QT_ * R), 256, 0, stream>>>(q, KV, nullptr, Opb, Ml, R);
        switch (R) {
            case 1: fa_merge<1><<<dim3(B_ * QT_ * 16), 256, 0, stream>>>(Opb, Ml, o); break;
            case 2: fa_merge<2><<<dim3(B_ * QT_ * 16), 256, 0, stream>>>(Opb, Ml, o); break;
            case 3: fa_merge<3><<<dim3(B_ * QT_ * 16), 256, 0, stream>>>(Opb, Ml, o); break;
            case 4: fa_merge<4><<<dim3(B_ * QT_ * 16), 256, 0, stream>>>(Opb, Ml, o); break;
            case 5: fa_merge<5><<<dim3(B_ * QT_ * 16), 256, 0, stream>>>(Opb, Ml, o); break;
            case 6: fa_merge<6><<<dim3(B_ * QT_ * 16), 256, 0, stream>>>(Opb, Ml, o); break;
            case 7: fa_merge<7><<<dim3(B_ * QT_ * 16), 256, 0, stream>>>(Opb, Ml, o); break;
            default: fa_merge<8><<<dim3(B_ * QT_ * 16), 256, 0, stream>>>(Opb, Ml, o); break;
        }
    } else {
        fa_fwd<false><<<dim3(B_ * QT_), 256, 0, stream>>>(q, KV, o, nullptr, nullptr, 1);
    }
}

// Round 11
// 124.555 us; speedup vs baseline: 1.2159x; 1.1636x over previous
//
#include <hip/hip_runtime.h>

// Causal single-head attention, B=4, S=4096, D=128, fp32 in/out.
// R11: globally-balanced split-K. Per batch, the 1056 k-tile visits
// (tile t owns visits [t(t+1),(t+1)(t+2)), local ktl = v - t(t+1)) are cut
// into 128 equal chunks (8-9 visits). 512 blocks, 256 thr, 32x32x16 core
// (R8, verified), 64KB LDS dbuf. Partials written in REGISTER ORDER
// (coalesced, no LDS bounce, no barriers); merge un-permutes.

#define B_   4
#define S_   4096
#define D_   128
#define NT_  64             // 64-key blobs per batch
#define QT_  32             // q-tiles per batch (BM=128)
#define JB   128            // chunks (blocks) per batch
#define W_   1056           // k-tile visits per batch = sum(2t+2)
#define SLOTS_PB 160        // >= JB + (QT_-1) segment slots per batch
#define BLOB_SHORTS 16384   // 32 KB per (b,kt): [K img 16KB][V^T img 16KB]
#define MASKVAL (-1.0e30f)

typedef __attribute__((ext_vector_type(8))) short bf16x8;
typedef __attribute__((ext_vector_type(4))) float f32x4;
typedef __attribute__((ext_vector_type(16))) float f32x16;

__device__ __forceinline__ short f2bf(float x) {
    unsigned u = __builtin_bit_cast(unsigned, x);
    unsigned r = (u + 0x7fffu + ((u >> 16) & 1u)) >> 16;
    return (short)r;
}
__device__ __forceinline__ float ex2(float x) { return __builtin_amdgcn_exp2f(x); }
__device__ __forceinline__ unsigned pkbf(float lo, float hi) {
    return (unsigned)(unsigned short)f2bf(lo) | ((unsigned)(unsigned short)f2bf(hi) << 16);
}
__device__ __forceinline__ float bf2f(short s) {
    return __builtin_bit_cast(float, ((unsigned)(unsigned short)s) << 16);
}
__device__ __forceinline__ void gl_lds16(const short* g, short* l) {
    __builtin_amdgcn_global_load_lds(
        (const __attribute__((address_space(1))) unsigned int*)g,
        (__attribute__((address_space(3))) unsigned int*)l, 16, 0, 0);
}
// chunk containing visit v (per batch): j = floor(v*JB/W) via 4/33 reduction
__device__ __forceinline__ int chunk_of(int v) { return (4 * v + 3) / 33; }

// ---------------- prep: 2048 blocks. Q(bf16,scaled)+K / V^T images ---------
__global__ __launch_bounds__(256) void prep(const float* __restrict__ Qg,
                                            const float* __restrict__ Kg,
                                            const float* __restrict__ Vg,
                                            short* __restrict__ Qbf,
                                            short* __restrict__ KV)
{
    __shared__ short vt[64][40];
    const int id  = blockIdx.x;
    const int tid = threadIdx.x;
    const float SC = 0.12751740f;   // log2(e)/sqrt(128)

    if (id < 1024) {
        const int b = id & 3, tile = (id >> 2) & 63, q4 = id >> 8;
        const int n = q4 * 16 + (tid >> 4);
        const int G = tid & 15;
        const size_t rowoff = ((size_t)b * S_ + (size_t)tile * 64 + n) * D_ + G * 8;
        short* blob = KV + (size_t)(b * NT_ + tile) * BLOB_SHORTS;
        {
            float4 a = *reinterpret_cast<const float4*>(Qg + rowoff);
            float4 c = *reinterpret_cast<const float4*>(Qg + rowoff + 4);
            bf16x8 v;
            v[0] = f2bf(a.x * SC); v[1] = f2bf(a.y * SC); v[2] = f2bf(a.z * SC); v[3] = f2bf(a.w * SC);
            v[4] = f2bf(c.x * SC); v[5] = f2bf(c.y * SC); v[6] = f2bf(c.z * SC); v[7] = f2bf(c.w * SC);
            *reinterpret_cast<bf16x8*>(Qbf + rowoff) = v;
        }
        {
            float4 a = *reinterpret_cast<const float4*>(Kg + rowoff);
            float4 c = *reinterpret_cast<const float4*>(Kg + rowoff + 4);
            bf16x8 v;
            v[0] = f2bf(a.x); v[1] = f2bf(a.y); v[2] = f2bf(a.z); v[3] = f2bf(a.w);
            v[4] = f2bf(c.x); v[5] = f2bf(c.y); v[6] = f2bf(c.z); v[7] = f2bf(c.w);
            const int p = (G & 8) | ((G & 7) ^ (n & 7));
            *reinterpret_cast<bf16x8*>(blob + n * 128 + p * 8) = v;
        }
    } else {
        const int u = id - 1024;
        const int b = u & 3, tile = (u >> 2) & 63, dq = u >> 8;
        short* blob = KV + (size_t)(b * NT_ + tile) * BLOB_SHORTS;
        {
            const int n = tid >> 2, c8 = tid & 3;
            const size_t off = ((size_t)b * S_ + (size_t)tile * 64 + n) * D_ + dq * 32 + c8 * 8;
            float4 a = *reinterpret_cast<const float4*>(Vg + off);
            float4 c = *reinterpret_cast<const float4*>(Vg + off + 4);
            bf16x8 v;
            v[0] = f2bf(a.x); v[1] = f2bf(a.y); v[2] = f2bf(a.z); v[3] = f2bf(a.w);
            v[4] = f2bf(c.x); v[5] = f2bf(c.y); v[6] = f2bf(c.z); v[7] = f2bf(c.w);
            *reinterpret_cast<bf16x8*>(&vt[n][c8 * 8]) = v;
        }
        __syncthreads();
        {
            const int dl = tid >> 3, G = tid & 7;
            const int d  = dq * 32 + dl;
            bf16x8 g;
#pragma unroll
            for (int i = 0; i < 8; ++i) g[i] = vt[G * 8 + i][dl];
            const int p = G ^ (d & 7);
            *reinterpret_cast<bf16x8*>(blob + 8192 + d * 64 + p * 8) = g;
        }
    }
}

// ---------------- fa_bal: 512 blocks, balanced visit chunks ----------------
// 32x32x16 MFMA layouts: A/B row(col)=lane&31, k=(lane>>5)*8+j;
// C/D col=lane&31, row=(reg&3)+8*(reg>>2)+4*(lane>>5).
__global__ __launch_bounds__(256, 2) void fa_bal(const short* __restrict__ Qbf,
                                                 const short* __restrict__ KV,
                                                 short* __restrict__ Opb,
                                                 float* __restrict__ Ml)
{
    __shared__ short lkv[2][BLOB_SHORTS];   // 64 KB double buffer

    const int tid  = threadIdx.x;
    const int wv   = tid >> 6;
    const int lane = tid & 63;
    const int col  = lane & 31;
    const int half = lane >> 5;
    const int c7   = col & 7;

    const int batch = blockIdx.x & 3;
    const int j     = blockIdx.x >> 2;          // 0..127
    const int v0    = (33 * j) >> 2;            // floor(j*W/JB)
    const int v1    = (33 * (j + 1)) >> 2;

    // initial tile/ktl from v0
    int t = (int)((sqrtf((float)(4 * v0 + 1)) - 1.0f) * 0.5f);
    while ((t + 1) * (t + 2) <= v0) ++t;
    while (t * (t + 1) > v0) --t;
    int ktl = v0 - t * (t + 1);

    // base(t) = sum of chunk-counts of tiles < t (slot numbering)
    int base = 0;
    for (int tt = 0; tt < t; ++tt) {
        int a = chunk_of(tt * (tt + 1));
        int b2 = chunk_of((tt + 1) * (tt + 2) - 1);
        base += b2 - a + 1;
    }
    int slot = batch * SLOTS_PB + base + (j - chunk_of(t * (t + 1)));

    const size_t tilebase = (size_t)batch * NT_ * BLOB_SHORTS;
#define STAGE(KT, BUF) do {                                                   \
        const short* g_ = KV + tilebase + (size_t)(KT) * BLOB_SHORTS + tid * 8;\
        short* l_ = (BUF) + tid * 8;                                          \
        _Pragma("unroll")                                                     \
        for (int c_ = 0; c_ < 8; ++c_)                                        \
            gl_lds16(g_ + c_ * 2048, l_ + c_ * 2048);                         \
    } while (0)
#define LOADQ(T) do {                                                         \
        const short* qp_ = Qbf + ((size_t)batch * S_ + (size_t)(T) * 128      \
                                  + wv * 32 + col) * D_ + half * 8;           \
        _Pragma("unroll")                                                     \
        for (int c_ = 0; c_ < 8; ++c_)                                        \
            qf[c_] = *reinterpret_cast<const bf16x8*>(qp_ + c_ * 16);         \
    } while (0)

    bf16x8 qf[8];
    LOADQ(t);

    f32x16 acc[4];
#pragma unroll
    for (int i = 0; i < 4; ++i)
#pragma unroll
        for (int r = 0; r < 16; ++r) acc[i][r] = 0.f;
    float mrun = MASKVAL, lrun = 0.f;

    STAGE(ktl, lkv[0]);

    for (int v = v0; v < v1; ++v) {
        const short* cur = lkv[(v - v0) & 1];
        short* nxt = lkv[(v - v0 + 1) & 1];

        // next visit's (tile, ktl)
        int nt = t, nktl = ktl + 1;
        if (nktl == 2 * t + 2) { nt = t + 1; nktl = 0; }

        __syncthreads();   // vmcnt(0) drain: cur staged; prev reads of nxt done
        if (v + 1 < v1) STAGE(nktl, nxt);

        const short* lk = cur;
        const short* lv = cur + 8192;

        // ---- S^T = K * Q^T
        f32x16 st[2];
#pragma unroll
        for (int i = 0; i < 2; ++i)
#pragma unroll
            for (int r = 0; r < 16; ++r) st[i][r] = 0.f;
#pragma unroll
        for (int c = 0; c < 8; ++c) {
            const int G = 2 * c + half;
            const int p = (G & 8) | ((G & 7) ^ c7);
#pragma unroll
            for (int kt32 = 0; kt32 < 2; ++kt32) {
                const int n = kt32 * 32 + col;
                bf16x8 kf = *reinterpret_cast<const bf16x8*>(lk + n * 128 + p * 8);
                st[kt32] = __builtin_amdgcn_mfma_f32_32x32x16_bf16(kf, qf[c], st[kt32], 0, 0, 0);
            }
        }

        // ---- causal mask (last two k-tiles of tile t)
        if (ktl >= 2 * t) {
            const int kbase = (ktl - 2 * t) * 64;
            const int qloc  = wv * 32 + col;
#pragma unroll
            for (int kt32 = 0; kt32 < 2; ++kt32)
#pragma unroll
                for (int r = 0; r < 16; ++r) {
                    const int kl = kt32 * 32 + (r & 3) + 8 * (r >> 2) + 4 * half;
                    if (kbase + kl > qloc) st[kt32][r] = MASKVAL;
                }
        }

        // ---- online softmax: per-lane + 1 shfl
        float mx = MASKVAL;
#pragma unroll
        for (int i = 0; i < 2; ++i)
#pragma unroll
            for (int r = 0; r < 16; ++r) mx = fmaxf(mx, st[i][r]);
        mx = fmaxf(mx, __shfl_xor(mx, 32));
        const float mnew = fmaxf(mrun, mx);
        const float al   = ex2(mrun - mnew);
        mrun = mnew;
        float sum = 0.f;
#pragma unroll
        for (int i = 0; i < 2; ++i)
#pragma unroll
            for (int r = 0; r < 16; ++r) {
                float pv = ex2(st[i][r] - mnew);
                st[i][r] = pv;
                sum += pv;
            }
        sum += __shfl_xor(sum, 32);
        lrun = lrun * al + sum;
#pragma unroll
        for (int i = 0; i < 4; ++i)
#pragma unroll
            for (int r = 0; r < 16; ++r) acc[i][r] *= al;

        // ---- PV: O^T += V^T * P^T
#pragma unroll
        for (int kt32 = 0; kt32 < 2; ++kt32) {
            unsigned pw[4][2];
#pragma unroll
            for (int w = 0; w < 4; ++w) {
                pw[w][0] = pkbf(st[kt32][4 * w],     st[kt32][4 * w + 1]);
                pw[w][1] = pkbf(st[kt32][4 * w + 2], st[kt32][4 * w + 3]);
            }
#pragma unroll
            for (int s1 = 0; s1 < 2; ++s1) {
                unsigned snd0 = pw[2 * s1 + 1 - half][0];
                unsigned snd1 = pw[2 * s1 + 1 - half][1];
                unsigned rcv0 = __shfl_xor((int)snd0, 32);
                unsigned rcv1 = __shfl_xor((int)snd1, 32);
                unsigned own0 = pw[2 * s1 + half][0];
                unsigned own1 = pw[2 * s1 + half][1];
                int4 wi;
                wi.x = (int)(half ? rcv0 : own0);
                wi.y = (int)(half ? rcv1 : own1);
                wi.z = (int)(half ? own0 : rcv0);
                wi.w = (int)(half ? own1 : rcv1);
                bf16x8 pf = __builtin_bit_cast(bf16x8, wi);
                const int G = 2 * (kt32 * 2 + s1) + half;
                const int p = G ^ c7;
#pragma unroll
                for (int dt = 0; dt < 4; ++dt) {
                    const int d = dt * 32 + col;
                    bf16x8 vf = *reinterpret_cast<const bf16x8*>(lv + d * 64 + p * 8);
                    acc[dt] = __builtin_amdgcn_mfma_f32_32x32x16_bf16(vf, pf, acc[dt], 0, 0, 0);
                }
            }
        }

        // ---- segment end: register-order partial write (coalesced, no LDS)
        if (nktl == 0 || v + 1 == v1) {
            short* ob = Opb + (size_t)slot * (128 * D_) + tid * 64;
#pragma unroll
            for (int dt = 0; dt < 4; ++dt)
#pragma unroll
                for (int g = 0; g < 4; ++g) {
                    int2 w;
                    w.x = (int)pkbf(acc[dt][4 * g],     acc[dt][4 * g + 1]);
                    w.y = (int)pkbf(acc[dt][4 * g + 2], acc[dt][4 * g + 3]);
                    *reinterpret_cast<int2*>(ob + (dt * 4 + g) * 4) = w;
                }
            if (half == 0) {
                float* mlb = Ml + (size_t)slot * (128 * 2) + (wv * 32 + col) * 2;
                mlb[0] = mrun;
                mlb[1] = lrun;
            }
            if (v + 1 < v1) {   // start next segment (tile nt)
                int a = chunk_of(t * (t + 1));
                int b2 = chunk_of((t + 1) * (t + 2) - 1);
                base += b2 - a + 1;
                slot = batch * SLOTS_PB + base + (j - chunk_of(nt * (nt + 1)));
                LOADQ(nt);
#pragma unroll
                for (int i = 0; i < 4; ++i)
#pragma unroll
                    for (int r = 0; r < 16; ++r) acc[i][r] = 0.f;
                mrun = MASKVAL; lrun = 0.f;
            }
        }
        t = nt; ktl = nktl;
    }
#undef STAGE
#undef LOADQ
}

// ---------------- merge: 2048 blocks, un-permutes register-order partials --
__global__ __launch_bounds__(256) void fa_merge(const short* __restrict__ Opb,
                                                const float* __restrict__ Ml,
                                                float* __restrict__ Og)
{
    const int x   = blockIdx.x;
    const int btq = x >> 4;                 // b*QT_ + t
    const int oct = x & 15;
    const int b   = btq >> 5;
    const int t   = btq & (QT_ - 1);
    const int q   = oct * 8 + (threadIdx.x >> 5);   // 0..127
    const int cg  = threadIdx.x & 31;

    // slots for this tile
    const int jlo = chunk_of(t * (t + 1));
    const int jhi = chunk_of((t + 1) * (t + 2) - 1);
    const int cnt = jhi - jlo + 1;
    int base = 0;
    for (int tt = 0; tt < t; ++tt) {
        int a = chunk_of(tt * (tt + 1));
        int b2 = chunk_of((tt + 1) * (tt + 2) - 1);
        base += b2 - a + 1;
    }
    const int slot0 = b * SLOTS_PB + base;

    // register-order read mapping
    const int t_id  = (q >> 5) * 64 + (cg & 1) * 32 + (q & 31);
    const int inner = (cg >> 3) * 4 + ((cg >> 1) & 3);
    const int d0    = (cg >> 3) * 32 + ((cg >> 1) & 3) * 8 + (cg & 1) * 4;

    float mg = MASKVAL;
    for (int r = 0; r < cnt; ++r)
        mg = fmaxf(mg, Ml[(size_t)(slot0 + r) * (128 * 2) + q * 2]);
    float l = 0.f;
    f32x4 a = (f32x4){0.f, 0.f, 0.f, 0.f};
    for (int r = 0; r < cnt; ++r) {
        const size_t sl = (size_t)(slot0 + r);
        float mr = Ml[sl * (128 * 2) + q * 2];
        float lr = Ml[sl * (128 * 2) + q * 2 + 1];
        float w  = ex2(mr - mg);
        l += lr * w;
        short4 s = *reinterpret_cast<const short4*>(
            Opb + sl * (128 * D_) + t_id * 64 + inner * 4);
        a[0] += w * bf2f(s.x);
        a[1] += w * bf2f(s.y);
        a[2] += w * bf2f(s.z);
        a[3] += w * bf2f(s.w);
    }
    *reinterpret_cast<f32x4*>(Og + (size_t)btq * (128 * D_) + q * D_ + d0) = a * (1.0f / l);
}

// ---------------- fallback: direct (no split), only if ws too small --------
__global__ __launch_bounds__(256, 2) void fa_direct(const short* __restrict__ Qbf,
                                                    const short* __restrict__ KV,
                                                    float* __restrict__ Og)
{
    __shared__ short lkv[2][BLOB_SHORTS];
    const int tid  = threadIdx.x;
    const int wv   = tid >> 6;
    const int lane = tid & 63;
    const int col  = lane & 31;
    const int half = lane >> 5;
    const int c7   = col & 7;
    const int batch = blockIdx.x & 3;
    const int t     = QT_ - 1 - (blockIdx.x >> 2);
    const int hi    = 2 * t + 2;

    bf16x8 qf[8];
    {
        const short* qp = Qbf + ((size_t)batch * S_ + (size_t)t * 128 + wv * 32 + col) * D_ + half * 8;
#pragma unroll
        for (int c = 0; c < 8; ++c) qf[c] = *reinterpret_cast<const bf16x8*>(qp + c * 16);
    }
    f32x16 acc[4];
#pragma unroll
    for (int i = 0; i < 4; ++i)
#pragma unroll
        for (int r = 0; r < 16; ++r) acc[i][r] = 0.f;
    float mrun = MASKVAL, lrun = 0.f;
    const size_t tilebase = (size_t)batch * NT_ * BLOB_SHORTS;
#define STAGE(KT, BUF) do {                                                   \
        const short* g_ = KV + tilebase + (size_t)(KT) * BLOB_SHORTS + tid * 8;\
        short* l_ = (BUF) + tid * 8;                                          \
        _Pragma("unroll")                                                     \
        for (int c_ = 0; c_ < 8; ++c_)                                        \
            gl_lds16(g_ + c_ * 2048, l_ + c_ * 2048);                         \
    } while (0)
    STAGE(0, lkv[0]);
    for (int kt = 0; kt < hi; ++kt) {
        const short* cur = lkv[kt & 1];
        short* nxt = lkv[(kt + 1) & 1];
        __syncthreads();
        if (kt + 1 < hi) STAGE(kt + 1, nxt);
        const short* lk = cur;
        const short* lv = cur + 8192;
        f32x16 st[2];
#pragma unroll
        for (int i = 0; i < 2; ++i)
#pragma unroll
            for (int r = 0; r < 16; ++r) st[i][r] = 0.f;
#pragma unroll
        for (int c = 0; c < 8; ++c) {
            const int G = 2 * c + half;
            const int p = (G & 8) | ((G & 7) ^ c7);
#pragma unroll
            for (int kt32 = 0; kt32 < 2; ++kt32) {
                const int n = kt32 * 32 + col;
                bf16x8 kf = *reinterpret_cast<const bf16x8*>(lk + n * 128 + p * 8);
                st[kt32] = __builtin_amdgcn_mfma_f32_32x32x16_bf16(kf, qf[c], st[kt32], 0, 0, 0);
            }
        }
        if (kt >= 2 * t) {
            const int kbase = (kt - 2 * t) * 64;
            const int qloc  = wv * 32 + col;
#pragma unroll
            for (int kt32 = 0; kt32 < 2; ++kt32)
#pragma unroll
                for (int r = 0; r < 16; ++r) {
                    const int kl = kt32 * 32 + (r & 3) + 8 * (r >> 2) + 4 * half;
                    if (kbase + kl > qloc) st[kt32][r] = MASKVAL;
                }
        }
        float mx = MASKVAL;
#pragma unroll
        for (int i = 0; i < 2; ++i)
#pragma unroll
            for (int r = 0; r < 16; ++r) mx = fmaxf(mx, st[i][r]);
        mx = fmaxf(mx, __shfl_xor(mx, 32));
        const float mnew = fmaxf(mrun, mx);
        const float al   = ex2(mrun - mnew);
        mrun = mnew;
        float sum = 0.f;
#pragma unroll
        for (int i = 0; i < 2; ++i)
#pragma unroll
            for (int r = 0; r < 16; ++r) {
                float pv = ex2(st[i][r] - mnew);
                st[i][r] = pv;
                sum += pv;
            }
        sum += __shfl_xor(sum, 32);
        lrun = lrun * al + sum;
#pragma unroll
        for (int i = 0; i < 4; ++i)
#pragma unroll
            for (int r = 0; r < 16; ++r) acc[i][r] *= al;
#pragma unroll
        for (int kt32 = 0; kt32 < 2; ++kt32) {
            unsigned pw[4][2];
#pragma unroll
            for (int w = 0; w < 4; ++w) {
                pw[w][0] = pkbf(st[kt32][4 * w],     st[kt32][4 * w + 1]);
                pw[w][1] = pkbf(st[kt32][4 * w + 2], st[kt32][4 * w + 3]);
            }
#pragma unroll
            for (int s1 = 0; s1 < 2; ++s1) {
                unsigned snd0 = pw[2 * s1 + 1 - half][0];
                unsigned snd1 = pw[2 * s1 + 1 - half][1];
                unsigned rcv0 = __shfl_xor((int)snd0, 32);
                unsigned rcv1 = __shfl_xor((int)snd1, 32);
                unsigned own0 = pw[2 * s1 + half][0];
                unsigned own1 = pw[2 * s1 + half][1];
                int4 wi;
                wi.x = (int)(half ? rcv0 : own0);
                wi.y = (int)(half ? rcv1 : own1);
                wi.z = (int)(half ? own0 : rcv0);
                wi.w = (int)(half ? own1 : rcv1);
                bf16x8 pf = __builtin_bit_cast(bf16x8, wi);
                const int G = 2 * (kt32 * 2 + s1) + half;
                const int p = G ^ c7;
#pragma unroll
                for (int dt = 0; dt < 4; ++dt) {
                    const int d = dt * 32 + col;
                    bf16x8 vf = *reinterpret_cast<const bf16x8*>(lv + d * 64 + p * 8);
                    acc[dt] = __builtin_amdgcn_mfma_f32_32x32x16_bf16(vf, pf, acc[dt], 0, 0, 0);
                }
            }
        }
    }
#undef STAGE
    const int qloc = wv * 32 + col;
    const float inv = 1.0f / lrun;
    float* og = Og + ((size_t)batch * S_ + (size_t)t * 128 + qloc) * D_;
#pragma unroll
    for (int dt = 0; dt < 4; ++dt)
#pragma unroll
        for (int g = 0; g < 4; ++g) {
            const int d0 = dt * 32 + 8 * g + 4 * half;
            f32x4 v4 = {acc[dt][4 * g] * inv, acc[dt][4 * g + 1] * inv,
                        acc[dt][4 * g + 2] * inv, acc[dt][4 * g + 3] * inv};
            *reinterpret_cast<f32x4*>(og + d0) = v4;
        }
}

extern "C" void kernel_launch(void* const* d_in, const int* in_sizes, int n_in,
                              void* d_out, int out_size, void* d_ws, size_t ws_size,
                              hipStream_t stream) {
    const float* q = (const float*)d_in[0];
    const float* k = (const float*)d_in[1];
    const float* v = (const float*)d_in[2];
    float* o = (float*)d_out;

    const size_t QBF_BYTES = (size_t)B_ * S_ * D_ * 2;              // 4 MB
    const size_t KV_BYTES  = (size_t)B_ * NT_ * BLOB_SHORTS * 2;    // 8 MB
    const size_t OP_BYTES  = (size_t)B_ * SLOTS_PB * 128 * D_ * 2;  // 21 MB
    const size_t ML_BYTES  = (size_t)B_ * SLOTS_PB * 128 * 2 * 4;   // 0.66 MB
    const size_t NEEDED    = QBF_BYTES + KV_BYTES + OP_BYTES + ML_BYTES;

    char* ws = (char*)d_ws;
    short* Qbf = (short*)ws;
    short* KV  = (short*)(ws + QBF_BYTES);

    prep<<<dim3(2048), 256, 0, stream>>>(q, k, v, Qbf, KV);

    if (ws_size >= NEEDED) {
        short* Opb = (short*)(ws + QBF_BYTES + KV_BYTES);
        float* Ml  = (float*)(ws + QBF_BYTES + KV_BYTES + OP_BYTES);
        fa_bal<<<dim3(B_ * JB), 256, 0, stream>>>(Qbf, KV, Opb, Ml);
        fa_merge<<<dim3(B_ * QT_ * 16), 256, 0, stream>>>(Opb, Ml, o);
    } else {
        fa_direct<<<dim3(B_ * QT_), 256, 0, stream>>>(Qbf, KV, o);
    }
}